// Round 1
// 280.565 us; speedup vs baseline: 1.3119x; 1.3119x over previous
//
#include <hip/hip_runtime.h>
#include <math.h>

typedef unsigned long long u64;
typedef unsigned int u32;

#define BF 8
#define NPTS 16384
#define HALFPTS 8192
#define M_SN 1024
#define CCH 64
#define KNN 16
#define NTHR1 1024
#define KPER 16            // NPTS / NTHR1
#define TBL 4096
#define CCAP 2048
#define REM 1008           // M - 16 gripper slots

// output layout (flat float32, concatenated in return order)
constexpr size_t O0 = 0;                 // neighbor_feats 8*1024*16*64
constexpr size_t O1 = 8388608;           // supernode_xyz 8*1024*3
constexpr size_t O2 = 8413184;           // neighbor_mask 8*1024*16
constexpr size_t O3 = 8544256;           // out_idx 8*1024
constexpr size_t O4 = 8552448;           // out_valid 8*1024
constexpr size_t O5 = 8560640;           // out_bucket 8*1024

// workspace layout: [0]=flag, PW_OFF: packed float4 points, then split wn lists
#define PW_OFF ((size_t)256)
#define PW_BYTES ((size_t)BF * NPTS * 16)          // 2 MiB
#define WN_BYTES ((size_t)2 * BF * M_SN * KNN * 8) // 2 MiB

__device__ __forceinline__ bool is_valid_el(const void* vp, int mode, long long i) {
  if (mode == 1) return ((const unsigned char*)vp)[i] != 0;
  if (mode == 2) return ((const float*)vp)[i] != 0.0f;
  return ((const int*)vp)[i] != 0;
}

// monotone-decreasing encode: larger float -> smaller u32 (NaN sorts first; -inf last)
__device__ __forceinline__ u32 desc_enc(float f) {
  u32 u = __float_as_uint(f);
  u32 s = (u & 0x80000000u) ? ~u : (u | 0x80000000u);
  return ~s;
}
__device__ __forceinline__ bool enc_finite(u32 d) {
  u32 s = ~d;
  u32 u = (s & 0x80000000u) ? (s & 0x7FFFFFFFu) : ~s;
  return (u & 0x7F800000u) != 0x7F800000u;
}

__device__ __forceinline__ u64 wave_min_u64(u64 v) {
#pragma unroll
  for (int d = 32; d >= 1; d >>= 1) {
    u32 lo = __shfl_xor((u32)(v & 0xFFFFFFFFu), d, 64);
    u32 hi = __shfl_xor((u32)(v >> 32), d, 64);
    u64 o = ((u64)hi << 32) | lo;
    if (o < v) v = o;
  }
  return v;
}

__device__ __forceinline__ u64 block_min_u64(u64 v, u64* red16, int t) {
  v = wave_min_u64(v);
  if ((t & 63) == 0) red16[t >> 6] = v;
  __syncthreads();
  if (t < 64) {
    u64 x = red16[t & 15];
    x = wave_min_u64(x);
    if (t == 0) red16[0] = x;
  }
  __syncthreads();
  u64 r = red16[0];
  __syncthreads();
  return r;
}

__device__ __forceinline__ int block_excl_scan(int val, int* scanb, int t, int* tot) {
  int incl = val;
#pragma unroll
  for (int d = 1; d < 64; d <<= 1) {
    int v = __shfl_up(incl, d, 64);
    if ((t & 63) >= d) incl += v;
  }
  if ((t & 63) == 63) scanb[t >> 6] = incl;
  __syncthreads();
  if (t < 64) {
    int ws = (t < 16) ? scanb[t] : 0;
#pragma unroll
    for (int d = 1; d < 16; d <<= 1) {
      int v = __shfl_up(ws, d, 64);
      if ((t & 63) >= d) ws += v;
    }
    if (t < 16) scanb[16 + t] = ws;
  }
  __syncthreads();
  int wv = t >> 6;
  int base = (wv == 0) ? 0 : scanb[16 + wv - 1];
  *tot = scanb[16 + 15];
  int r = base + incl - val;
  __syncthreads();
  return r;
}

__device__ __forceinline__ u64 shfl64_grp(u64 v, int src) {   // width-32 partitioned
  u32 lo = (u32)__shfl((int)(u32)(v & 0xFFFFFFFFu), src, 32);
  u32 hi = (u32)__shfl((int)(u32)(v >> 32), src, 32);
  return ((u64)hi << 32) | lo;
}

// ---------------------------------------------------------------------------
// topk_select: exact ordered top-T of (ek asc, idx asc) among cmask candidates.
// Histogram into bins (monotone non-decreasing in ek) -> scan -> cut-bucket B
// -> collect candidates grouped by bin -> exact rank within bin segment only.
// Writes winner r (< T) to outArr[r] as idx (| 0x80000000 if enc non-finite).
// On candidate overflow (> CCAP) sets sh[7]=0 and leaves outArr untouched;
// caller must run its fallback. outArr slots must be pre-initialized to -1.
// ---------------------------------------------------------------------------
template<bool ASC, bool SHIFTBIN>
__device__ __forceinline__ void topk_select(const u32* ek, const u32* bk, u32 cmask,
    int Twant, int* table, u64* cand, int* scanb, int* sh, int* outArr, int t) {
  for (int j = t; j < TBL; j += NTHR1) table[j] = 0;
  if (t == 6) sh[6] = 0x7FFFFFFF;
  if (t == 7) sh[7] = 1;
  __syncthreads();
#pragma unroll
  for (int k = 0; k < KPER; k++) {
    if ((cmask >> k) & 1u) {
      int bin = SHIFTBIN ? (int)(ek[k] >> 20) : (int)bk[k];
      atomicAdd(&table[bin], 1);
    }
  }
  __syncthreads();
  int c_[4]; int c4 = 0;
#pragma unroll
  for (int q = 0; q < 4; q++) { c_[q] = table[4 * t + q]; c4 += c_[q]; }
  int htot;
  int cum = block_excl_scan(c4, scanb, t, &htot);
  const int T = min(Twant, htot);
  int e_ = cum;
#pragma unroll
  for (int q = 0; q < 4; q++) {
    int nx = e_ + c_[q];
    if (T > 0 && e_ < T && nx >= T) atomicMin(&sh[6], 4 * t + q);
    table[4 * t + q] = e_;           // overwrite counts with exclusive cums
    e_ = nx;
  }
  __syncthreads();
  if (T <= 0) return;                // uniform; outArr stays -1; sh[7] stays 1
  const int B = sh[6];
#pragma unroll
  for (int k = 0; k < KPER; k++) {
    if ((cmask >> k) & 1u) {
      int bin = SHIFTBIN ? (int)(ek[k] >> 20) : (int)bk[k];
      if (bin <= B) {
        int pos = atomicAdd(&table[bin], 1);   // grouped placement per bin
        if (pos < CCAP)
          cand[pos] = ((u64)ek[k] << 32) | ((u64)(u32)bin << 14) | (u32)(k * NTHR1 + t);
      }
    }
  }
  __syncthreads();
  const int nc = table[B];           // inclusive end of bin B == total collected
  if (nc <= CCAP) {
    for (int c = t; c < nc; c += NTHR1) {
      u64 key = cand[c];
      int bin = (int)((key >> 14) & 0xFFFu);
      int s = bin ? table[bin - 1] : 0;        // segment start (end of bin-1)
      int e2 = table[bin];                     // segment end
      int r = s;
      for (int j = s; j < e2; j++) r += (cand[j] < key);
      if (r < T) {
        u32 enc = (u32)(key >> 32);
        int ix = (int)(key & 0x3FFFu);
        bool fin = ASC ? (enc < 0x7F800000u) : enc_finite(enc);
        outArr[r] = fin ? ix : (ix | (int)0x80000000);
      }
    }
  } else {
    if (t == 0) sh[7] = 0;
  }
  __syncthreads();
}

// ---------------- K0: detect how `valid` (bool) is stored ----------------
__global__ void detect_valid(const unsigned* __restrict__ w, int nwords, int* __restrict__ flag) {
  __shared__ int cls;
  int t = threadIdx.x;
  if (t == 0) cls = 0;
  __syncthreads();
  int local = 0;
  for (int i = t; i < nwords; i += blockDim.x) {
    unsigned v = w[i];
    if (v == 0x3F800000u) local = 2;
    else if (v != 0u && v != 1u) local = max(local, 1);
  }
  if (local) atomicMax(&cls, local);
  __syncthreads();
  if (t == 0) flag[0] = cls;
}

// ---------------- K1: supernode sampling (one block per batch row) ----------------
__global__ __launch_bounds__(1024)
void sample_kernel(const float* __restrict__ xyz, const void* __restrict__ validp,
                   const float* __restrict__ state, const int* __restrict__ mask_id,
                   const float* __restrict__ extra, const float* __restrict__ glob,
                   const int* __restrict__ flagp, float4* __restrict__ pw,
                   float* __restrict__ out) {
  __shared__ u64 red16[16];
  __shared__ int table[TBL];        // 16 KB
  __shared__ int scanb[32];
  __shared__ int mpick[REM];
  __shared__ u64 cand[CCAP];        // 16 KB
  __shared__ int gsorted[REM];
  __shared__ int head_i[16];
  __shared__ int head_bk[16];
  __shared__ int sh[8];             // 0:rhv 1:first_valid 2:has_radius 6:B 7:ok

  const int b = blockIdx.x, t = threadIdx.x;
  const int vmode = flagp[0];
  const float* xyzb = xyz + (size_t)b * NPTS * 3;
  const int* midb = mask_id + (size_t)b * NPTS;
  const float* exb = extra + (size_t)b * NPTS;
  const float* glb = glob + (size_t)b * NPTS;

  if (t < 8) sh[t] = 0;
  if (t == 1) sh[1] = 0x7FFFFFFF;
  if (t < 16) gsorted[t] = -1;      // gripper winners default
  __syncthreads();

  // ---- validity bits (element i = k*1024 + t) ----
  u32 vbits = 0;
#pragma unroll
  for (int k = 0; k < KPER; k++) {
    int i = k * NTHR1 + t;
    if (is_valid_el(validp, vmode, (long long)b * NPTS + i)) vbits |= 1u << k;
  }
  if (vbits) {
    atomicOr(&sh[0], 1);
    atomicMin(&sh[1], (__ffs(vbits) - 1) * NTHR1 + t);
  }

  // ---- gripper distances + packed point array for knn ----
  float gx = state[b * 8 + 0], gy = state[b * 8 + 1], gz = state[b * 8 + 2];
  float gd[KPER];
  u32 inr = 0;
#pragma unroll
  for (int k = 0; k < KPER; k++) {
    int i = k * NTHR1 + t;
    float px = xyzb[3 * i], py = xyzb[3 * i + 1], pz = xyzb[3 * i + 2];
    float dx = px - gx, dy = py - gy, dz = pz - gz;
    float d = sqrtf((dx * dx + dy * dy) + dz * dz);
    gd[k] = d;
    bool vb = (vbits >> k) & 1u;
    if (vb && d <= 0.1f) inr |= 1u << k;
    if (pw) {
      // EXACT same |p|^2 arithmetic as knn's old staging (bit-identical d2)
      float sb = __fadd_rn(__fadd_rn(__fmul_rn(px, px), __fmul_rn(py, py)), __fmul_rn(pz, pz));
      pw[(size_t)b * NPTS + i] = make_float4(px, py, pz, vb ? sb : INFINITY);
    }
  }
  if (inr) atomicOr(&sh[2], 1);
  __syncthreads();

  const int rhv = sh[0];
  const int first_valid = rhv ? sh[1] : 0;
  const u32 elig = vbits & (sh[2] ? inr : 0xFFFFu);
  u32 sel = 0;

  // ---- gripper: exact ordered top-16 of (gdist asc, idx asc) over eligible ----
  {
    u32 ek[KPER];
#pragma unroll
    for (int k = 0; k < KPER; k++) ek[k] = __float_as_uint(gd[k]);  // gd>=0: bits asc
    topk_select<true, true>(ek, nullptr, elig, 16, table, cand, scanb, sh, gsorted, t);
    if (sh[7]) {
      if (t < 16) {
        int g = gsorted[t];
        head_i[t] = (g >= 0) ? g : first_valid;
        head_bk[t] = (g >= 0) ? 1 : -1;
      }
      __syncthreads();
      for (int j = 0; j < 16; j++) {
        if (head_bk[j] == 1) {
          int ix = head_i[j];
          if ((ix & (NTHR1 - 1)) == t) sel |= 1u << (ix >> 10);
        }
      }
    } else {
      // pathological-ties fallback: old iterative extraction
      for (int it = 0; it < 16; ++it) {
        u64 best = ~0ull;
#pragma unroll
        for (int k = 0; k < KPER; k++) {
          if (((elig >> k) & 1u) && !((sel >> k) & 1u)) {
            u64 key = ((u64)__float_as_uint(gd[k]) << 32) | (u32)(k * NTHR1 + t);
            if (key < best) best = key;
          }
        }
        u64 w = block_min_u64(best, red16, t);
        bool keep = (w >> 32) < 0x7F800000ull;
        int idx = (int)(w & 0xFFFFFFFFu);
        if (t == 0) { head_i[it] = keep ? idx : first_valid; head_bk[it] = keep ? 1 : -1; }
        if (keep && (idx & (NTHR1 - 1)) == t) sel |= 1u << (idx >> 10);
      }
      __syncthreads();
    }
  }

  // ---- mask stage: min index per distinct mask_id among candidates ----
  for (int j = t; j < TBL; j += NTHR1) table[j] = 0x7FFFFFFF;
  __syncthreads();
#pragma unroll
  for (int k = 0; k < KPER; k++) {
    if (((vbits >> k) & 1u) && !((sel >> k) & 1u)) {
      int i = k * NTHR1 + t;
      int id = midb[i];
      if ((u32)id < TBL) atomicMin(&table[id], i);
    }
  }
  __syncthreads();
  int cnt = 0;
#pragma unroll
  for (int q = 0; q < 4; q++) cnt += (table[4 * t + q] != 0x7FFFFFFF);
  int mtot;
  int excl = block_excl_scan(cnt, scanb, t, &mtot);
  {
    int pos = excl;
#pragma unroll
    for (int q = 0; q < 4; q++) {
      int v = table[4 * t + q];
      if (v != 0x7FFFFFFF) { if (pos < REM) mpick[pos] = v; pos++; }
    }
  }
  __syncthreads();
  const int nm = min(mtot, REM);
  for (int j = 0; j < nm; j++) {
    int p = mpick[j];
    if ((p & (NTHR1 - 1)) == t) sel |= 1u << (p >> 10);
  }

  // ---- extra stage (only active when < 8 distinct mask ids) ----
  u32 extra_used = 0;
  if (nm < 8 && rhv) {
    u32 extrbits = 0;
    for (int j = 0; j < 8; j++) {
      u64 best = ~0ull;
#pragma unroll
      for (int k = 0; k < KPER; k++) {
        if (((vbits >> k) & 1u) && !((sel >> k) & 1u) && !((extrbits >> k) & 1u)) {
          int i = k * NTHR1 + t;
          u64 key = ((u64)desc_enc(exb[i]) << 32) | (u32)i;
          if (key < best) best = key;
        }
      }
      u64 w = block_min_u64(best, red16, t);
      if (w == ~0ull) break;
      int idx = (int)(w & 0xFFFFFFFFu);
      bool fin = enc_finite((u32)(w >> 32));
      if ((idx & (NTHR1 - 1)) == t) extrbits |= 1u << (idx >> 10);
      if (j >= nm && fin) {
        extra_used |= 1u << j;
        if (t == 0) mpick[j] = idx;
        if ((idx & (NTHR1 - 1)) == t) sel |= 1u << (idx >> 10);
      }
    }
    __syncthreads();
  }

  // ---- global stage: exact ordered top-1008 of (global_score desc, idx asc) ----
  {
    u32 cbits = vbits & ~sel;
    u32 ek[KPER], bk[KPER];
#pragma unroll
    for (int k = 0; k < KPER; k++) {
      if ((cbits >> k) & 1u) {
        float f = glb[k * NTHR1 + t];
        ek[k] = desc_enc(f);
        // value-linear bins for uniform-ish scores: ~4 candidates/bin instead of
        // ~960/bin with exponent bins. Monotone non-decreasing in ek for finite f;
        // equal-bin ties resolved by exact key compare -> rank stays exact.
        float g = fminf(fmaxf(f, 0.0f), 0.99999994f);
        bk[k] = 4095u - (u32)(g * 4096.0f);
      } else { ek[k] = 0xFFFFFFFFu; bk[k] = 4095u; }
    }
    for (int j = t; j < REM; j += NTHR1) gsorted[j] = -1;
    topk_select<false, false>(ek, bk, cbits, REM, table, cand, scanb, sh, gsorted, t);
    if (!sh[7]) {
      // pathological-ties fallback: old iterative extraction
      u32 gext = 0;
      for (int j = 0; j < REM; j++) {
        u64 best = ~0ull;
#pragma unroll
        for (int k = 0; k < KPER; k++) {
          if (((cbits >> k) & 1u) && !((gext >> k) & 1u)) {
            u64 key = ((u64)ek[k] << 32) | (u32)(k * NTHR1 + t);
            if (key < best) best = key;
          }
        }
        u64 w = block_min_u64(best, red16, t);
        if (w == ~0ull) break;
        int idx = (int)(w & 0xFFFFFFFFu);
        if ((idx & (NTHR1 - 1)) == t) gext |= 1u << (idx >> 10);
        if (t == 0) gsorted[j] = enc_finite((u32)(w >> 32)) ? idx : (idx | (int)0x80000000);
      }
      __syncthreads();
    }
  }

  // ---- emit out_idx / out_valid / out_bucket / supernode_xyz ----
  {
    int slot = t;
    int idx, bucket;
    if (slot < 16) {
      idx = head_i[slot];
      bucket = head_bk[slot];
    } else {
      int jj = slot - 16;
      bool mk = (jj < nm) || (jj < 8 && ((extra_used >> jj) & 1u));
      if (mk) { idx = mpick[jj]; bucket = 2; }
      else {
        int g = gsorted[jj];
        if (rhv && g >= 0) { idx = g; bucket = 0; }
        else { idx = first_valid; bucket = -1; }
      }
    }
    bool ov = rhv && is_valid_el(validp, vmode, (long long)b * NPTS + idx);
    int ob = ov ? bucket : -1;
    size_t o = (size_t)b * M_SN + slot;
    out[O3 + o] = (float)idx;
    out[O4 + o] = ov ? 1.0f : 0.0f;
    out[O5 + o] = (float)ob;
    out[O1 + 3 * o + 0] = xyzb[3 * idx + 0];
    out[O1 + 3 * o + 1] = xyzb[3 * idx + 1];
    out[O1 + 3 * o + 2] = xyzb[3 * idx + 2];
  }
}

// ---------------- K2: KNN-16 distance scan ----------------
// 8 supernodes per block of 256 threads; supernode = contiguous 32-lane group.
// Distributed sorted list (ld2,lidx) across the 32 lanes; kth = group 16th-best
// d2 replicated as a float. Hot loop compares FLOAT d2 only (exact: points
// arrive in ascending idx, so strict < reproduces (d2,idx) tie order).
// grid.y=2 splits the point range; tiny merge kernel combines (exact).
#define NTHR2 256
#define CH 1024
#define SPB 8

__global__ __launch_bounds__(256, 8)
void knn_kernel(const float* __restrict__ x, const float* __restrict__ xyz,
                const void* __restrict__ validp, const int* __restrict__ flagp,
                const float4* __restrict__ pw, u64* __restrict__ wnws,
                float* __restrict__ out) {
  __shared__ __align__(16) float4 st[CH];           // 16 KB
  __shared__ u64 wn[SPB * KNN];

  const int b = blockIdx.x >> 7;
  const int grp = blockIdx.x & 127;
  const int half = blockIdx.y;
  const int t = threadIdx.x;
  const int sl = t >> 5;
  const int sub = t & 31;
  const int lanebase = t & 32;
  const int m = grp * SPB + sl;
  const int vmode = flagp[0];
  const float* xyzb = xyz + (size_t)b * NPTS * 3;

  const int sidx = (int)out[O3 + (size_t)b * M_SN + m];
  float ax, ay, az;
  if (pw) { float4 q = pw[(size_t)b * NPTS + sidx]; ax = q.x; ay = q.y; az = q.z; }
  else { ax = xyzb[3 * sidx]; ay = xyzb[3 * sidx + 1]; az = xyzb[3 * sidx + 2]; }
  const float sa = __fadd_rn(__fadd_rn(__fmul_rn(ax, ax), __fmul_rn(ay, ay)), __fmul_rn(az, az));

  float ld2 = INFINITY;   // lane sub = sub-th smallest d2 seen so far
  int lidx = 0;
  float kth = INFINITY;   // group 16th-best d2 (replicated)

  const int cbeg = wnws ? half * HALFPTS : 0;
  const int cend = wnws ? cbeg + HALFPTS : NPTS;

  for (int c0 = cbeg; c0 < cend; c0 += CH) {
    if (pw) {
      const float4* src = pw + (size_t)b * NPTS + c0;
#pragma unroll
      for (int q = 0; q < CH / NTHR2; q++) st[t + q * NTHR2] = src[t + q * NTHR2];
    } else {
      for (int p = t; p < CH; p += NTHR2) {
        float px = xyzb[3 * (c0 + p)], py = xyzb[3 * (c0 + p) + 1], pz = xyzb[3 * (c0 + p) + 2];
        bool v = is_valid_el(validp, vmode, (long long)b * NPTS + c0 + p);
        float sb = __fadd_rn(__fadd_rn(__fmul_rn(px, px), __fmul_rn(py, py)), __fmul_rn(pz, pz));
        st[p] = make_float4(px, py, pz, v ? sb : INFINITY);
      }
    }
    __syncthreads();
#pragma unroll 4
    for (int j = 0; j < CH / 32; j++) {
      float4 v = st[sub + 32 * j];
      // bit-identical d2 arithmetic to previous kernel
      float dot = __fadd_rn(__fadd_rn(__fmul_rn(ax, v.x), __fmul_rn(ay, v.y)), __fmul_rn(az, v.z));
      float d2 = fmaxf(__fsub_rn(__fadd_rn(sa, v.w), __fmul_rn(2.0f, dot)), 0.0f);
      u64 bal = __ballot(d2 < kth);
      u32 mq = (u32)(bal >> lanebase);
      while (mq) {
        int bb = __ffs(mq) - 1;
        mq &= mq - 1;
        float kd = __shfl(d2, lanebase + bb, 64);
        if (kd < kth) {                       // group-uniform re-check
          int ki = c0 + 32 * j + bb;          // candidate idx (no shuffle needed)
          bool gt = ld2 > kd;
          float sd = __shfl_up(ld2, 1, 32);
          int si = __shfl_up(lidx, 1, 32);
          int pg = __shfl_up(gt ? 1 : 0, 1, 32);
          if (sub == 0) pg = 0;
          ld2 = gt ? (pg ? sd : kd) : ld2;
          lidx = gt ? (pg ? si : ki) : lidx;
          kth = __shfl(ld2, 15, 32);
        }
      }
    }
    __syncthreads();
  }

  if (wnws) {
    if (sub < KNN)
      wnws[((size_t)half * BF + b) * M_SN * KNN + (size_t)m * KNN + sub] =
          ((u64)__float_as_uint(ld2) << 32) | (u32)lidx;
    return;
  }

  // non-split fallback: emit directly
  if (sub < KNN) wn[sl * KNN + sub] = ((u64)__float_as_uint(ld2) << 32) | (u32)lidx;
  __syncthreads();
  {
    int s2 = t >> 5;
    int k2 = (t >> 1) & 15;
    int hf = t & 1;
    int mm = grp * SPB + s2;
    u64 key = wn[s2 * KNN + k2];
    int ni = (int)(key & (u64)(NPTS - 1));
    size_t o2 = ((size_t)b * M_SN + mm) * KNN + k2;
    if (hf == 0) out[O2 + o2] = ((u32)(key >> 32) < 0x7F800000u) ? 1.0f : 0.0f;
    const float4* src = (const float4*)(x + ((size_t)b * NPTS + ni) * CCH);
    float4* dst = (float4*)(out + O0 + o2 * CCH);
#pragma unroll
    for (int q = 0; q < 8; q++) dst[hf * 8 + q] = src[hf * 8 + q];
  }
}

// ---------------- K3: merge the two half-range top-16 lists + emit ----------------
__global__ __launch_bounds__(256)
void knn_merge_kernel(const float* __restrict__ x, const u64* __restrict__ wnws,
                      float* __restrict__ out) {
  __shared__ u64 wn[SPB * KNN];
  const int b = blockIdx.x >> 7;
  const int grp = blockIdx.x & 127;
  const int t = threadIdx.x;
  const int sl = t >> 5;
  const int sub = t & 31;
  const int m = grp * SPB + sl;

  // lanes 0-15: half0 list, lanes 16-31: half1 list (each sorted ascending)
  const int h = sub >> 4, k = sub & 15;
  u64 my = wnws[((size_t)h * BF + b) * M_SN * KNN + (size_t)m * KNN + k];
  const int obase = (1 - h) << 4;
  int cnt2 = 0;
#pragma unroll
  for (int j = 0; j < 16; j++) {
    u64 o = shfl64_grp(my, obase + j);
    cnt2 += h ? (o <= my) : (o < my);   // stable merge: half0 wins ties
  }
  int rank = k + cnt2;
  if (rank < KNN) wn[sl * KNN + rank] = my;
  __syncthreads();

  {
    int s2 = t >> 5;
    int k2 = (t >> 1) & 15;
    int hf = t & 1;
    int mm = grp * SPB + s2;
    u64 key = wn[s2 * KNN + k2];
    int ni = (int)(key & (u64)(NPTS - 1));
    size_t o2 = ((size_t)b * M_SN + mm) * KNN + k2;
    if (hf == 0) out[O2 + o2] = ((u32)(key >> 32) < 0x7F800000u) ? 1.0f : 0.0f;
    const float4* src = (const float4*)(x + ((size_t)b * NPTS + ni) * CCH);
    float4* dst = (float4*)(out + O0 + o2 * CCH);
#pragma unroll
    for (int q = 0; q < 8; q++) dst[hf * 8 + q] = src[hf * 8 + q];
  }
}

extern "C" void kernel_launch(void* const* d_in, const int* in_sizes, int n_in,
                              void* d_out, int out_size, void* d_ws, size_t ws_size,
                              hipStream_t stream) {
  const float* x = (const float*)d_in[0];
  const float* xyz = (const float*)d_in[1];
  const void* valid = d_in[2];
  const float* state = (const float*)d_in[3];
  const int* mask_id = (const int*)d_in[4];
  const float* extra = (const float*)d_in[5];
  const float* glob = (const float*)d_in[6];
  float* out = (float*)d_out;
  int* flag = (int*)d_ws;

  float4* pw = nullptr;
  u64* wnws = nullptr;
  if (ws_size >= PW_OFF + PW_BYTES) pw = (float4*)((char*)d_ws + PW_OFF);
  if (pw && ws_size >= PW_OFF + PW_BYTES + WN_BYTES)
    wnws = (u64*)((char*)d_ws + PW_OFF + PW_BYTES);

  detect_valid<<<1, 1024, 0, stream>>>((const unsigned*)valid, in_sizes[2] / 4, flag);
  sample_kernel<<<BF, NTHR1, 0, stream>>>(xyz, valid, state, mask_id, extra, glob, flag, pw, out);
  dim3 kg(BF * 128, wnws ? 2 : 1);
  knn_kernel<<<kg, NTHR2, 0, stream>>>(x, xyz, valid, flag, pw, wnws, out);
  if (wnws) knn_merge_kernel<<<BF * 128, NTHR2, 0, stream>>>(x, wnws, out);
}